// Round 9
// baseline (498.016 us; speedup 1.0000x reference)
//
#include <hip/hip_runtime.h>
#include <hip/hip_fp16.h>
#include <math.h>

#define H 1024
#define V 18
#define NUM_NODES 7
#define LEN 40
#define BATCH 512
#define NWG 256
#define NT 512
#define WROW 528   // u32 stride of LDS weight rows (bank-spread padding)

#define AGENT __HIP_MEMORY_SCOPE_AGENT
typedef unsigned long long u64;
typedef _Float16 half2v __attribute__((ext_vector_type(2)));

// ws: u64 h1s[2][1024], u64 h2s[2][1024], f32 c1buf[1024], f32 c2buf[1024]
#define WS_ZERO_U32 (8192 + 2048)

__device__ __forceinline__ float wred64(float v) {
#pragma unroll
  for (int off = 32; off > 0; off >>= 1) v += __shfl_xor(v, off, 64);
  return v;
}
__device__ __forceinline__ float sigm(float x) { return 1.0f / (1.0f + expf(-x)); }
__device__ __forceinline__ float dot4(float4 a, float4 b) {
  return a.x * b.x + a.y * b.y + a.z * b.z + a.w * b.w;
}
__device__ __forceinline__ float fdot2_(unsigned w, unsigned h, float c) {
  half2v a = __builtin_bit_cast(half2v, w);
  half2v b = __builtin_bit_cast(half2v, h);
#if __has_builtin(__builtin_amdgcn_fdot2)
  return __builtin_amdgcn_fdot2(a, b, c, false);
#else
  return c + (float)a.x * (float)b.x + (float)a.y * (float)b.y;
#endif
}

// 4 rows (slotbase+g, g=lane>>4) dotted with hp simultaneously; 16-lane groups.
// Returns all 4 sums, uniform across the wave.
__device__ __forceinline__ float4 dot4rows(const unsigned (*wl)[WROW], int slotbase,
                                           const unsigned* hp, int g16, int r16) {
  const unsigned* wr = wl[slotbase + g16];
  float a0 = 0.f, a1 = 0.f;
#pragma unroll
  for (int k = 0; k < 16; k += 2) {
    uint2 w0 = *(const uint2*)(wr + 2 * r16 + 32 * k);
    uint2 h0 = *(const uint2*)(hp + 2 * r16 + 32 * k);
    uint2 w1 = *(const uint2*)(wr + 2 * r16 + 32 * (k + 1));
    uint2 h1 = *(const uint2*)(hp + 2 * r16 + 32 * (k + 1));
    a0 = fdot2_(w0.x, h0.x, a0); a0 = fdot2_(w0.y, h0.y, a0);
    a1 = fdot2_(w1.x, h1.x, a1); a1 = fdot2_(w1.y, h1.y, a1);
  }
  float a = a0 + a1;
  a += __shfl_xor(a, 1); a += __shfl_xor(a, 2);
  a += __shfl_xor(a, 4); a += __shfl_xor(a, 8);
  float4 r;
  r.x = __shfl(a, 0);  r.y = __shfl(a, 16);
  r.z = __shfl(a, 32); r.w = __shfl(a, 48);
  return r;
}

__global__ void __launch_bounds__(256) init_ws_kernel(unsigned* p, int n) {
  int i = blockIdx.x * 256 + threadIdx.x;
  if (i < n) p[i] = 0u;
}

__global__ void __launch_bounds__(NT) decoder_kernel(
    const int* __restrict__ x0,
    const float* __restrict__ emb,    // [V][H]
    const float* __restrict__ w_ih,   // [L][4H][H]
    const float* __restrict__ w_hh,   // [L][4H][H]
    const float* __restrict__ b_ih,   // [L][4H]
    const float* __restrict__ b_hh,   // [L][4H]
    const float* __restrict__ w_fc,   // [V][H]
    const float* __restrict__ b_fc,   // [V]
    float* __restrict__ out,
    float* __restrict__ ws)
{
  u64* h1s = (u64*)ws;               // [2][1024] (tag<<32 | f32 bits)
  u64* h2s = h1s + 2 * H;            // [2][1024]
  float* c1buf = (float*)(h2s + 2 * H);
  float* c2buf = c1buf + H;

  float* out_tok  = out;                           // [LEN][BATCH] (as float)
  float* out_outs = out + LEN * BATCH;             // [BATCH][V]
  float* out_hf   = out_outs + BATCH * V;          // [2][BATCH][H]
  float* out_cf   = out_hf + 2 * BATCH * H;        // [2][BATCH][H]

  const int wg = blockIdx.x, tid = threadIdx.x;
  const int wave = tid >> 6, lane = tid & 63;
  const int g16 = lane >> 4, r16 = lane & 15;

  // weight slots: [0..15] wh0 (s=u*4+q), [16..31] wi1, [32..47] wh1, [48..65] wfc[v]
  __shared__ __align__(16) unsigned wlds[66][WROW];     // ~139 KB
  __shared__ __align__(16) unsigned h1p[512], h2p[512]; // f16-packed h vectors
  __shared__ float s_eix[4][4][V];   // [u][q][v] = wi0 . emb[v] + b0
  __shared__ float s_logits[V];
  __shared__ float s_bfc[V];

  // ---- prologue 1: stage weights (fp32 global -> f16 LDS) ----
  for (int i = tid; i < 66 * 512; i += NT) {
    const int slot = i >> 9, p = i & 511;
    const int s = slot & 15, q = s & 3, uu = s >> 2;
    const float* src;
    if (slot < 16)      src = w_hh + (size_t)(q * H + wg * 4 + uu) * H;
    else if (slot < 32) src = w_ih + (size_t)(4 * H + q * H + wg * 4 + uu) * H;
    else if (slot < 48) src = w_hh + (size_t)(4 * H + q * H + wg * 4 + uu) * H;
    else                src = w_fc + (size_t)(slot - 48) * H;
    float2 f = *(const float2*)(src + 2 * p);
    __half2 hh = __floats2half2_rn(f.x, f.y);
    wlds[slot][p] = *(unsigned*)&hh;
  }
  if (tid < V) s_bfc[tid] = b_fc[tid];
  h1p[tid] = 0u; h2p[tid] = 0u;

  // ---- prologue 2: eix[u][q][v] (fp32, one-time) ----
#pragma unroll
  for (int rr = 0; rr < 2; ++rr) {
    const int idx = wave * 2 + rr;          // 0..15
    const int q = idx & 3, uu = idx >> 2;
    const int row = q * H + wg * 4 + uu;
    const float4* wp = (const float4*)(w_ih + (size_t)row * H);
    float4 wv[4];
#pragma unroll
    for (int m = 0; m < 4; ++m) wv[m] = wp[lane + 64 * m];
    const float b0 = b_ih[row] + b_hh[row];
    for (int v = 0; v < V; ++v) {
      const float4* er = (const float4*)(emb + (size_t)v * H);
      float a = 0.f;
#pragma unroll
      for (int m = 0; m < 4; ++m) a += dot4(wv[m], er[lane + 64 * m]);
      a = wred64(a);
      if (lane == 0) s_eix[uu][q][v] = a + b0;
    }
  }
  // layer-2 biases for waves 0..3 (unit j = wg*4+wave)
  float bs1[4] = {0.f, 0.f, 0.f, 0.f};
  if (wave < 4) {
    const int j = wg * 4 + wave;
#pragma unroll
    for (int q = 0; q < 4; ++q)
      bs1[q] = b_ih[4 * H + q * H + j] + b_hh[4 * H + q * H + j];
  }
  __syncthreads();

  int tok = x0[0];
  float c1 = 0.f, c2 = 0.f;
  float4 pre0 = {0.f, 0.f, 0.f, 0.f};   // wh0 . h1(t-1), from previous B-wait
  float4 pre1 = {0.f, 0.f, 0.f, 0.f};   // wh1 . h2(t-1), from this A-wait

  for (int t = 0; t < LEN; ++t) {
    const int pw = t & 1;
    const unsigned tag = (unsigned)(t + 1);

    // ---------- Phase A: layer-0 gates = eix[.][tok] + pre0; publish h1 ----------
    if (wave < 4) {
      const float ga0 = pre0.x + s_eix[wave][0][tok];
      const float ga1 = pre0.y + s_eix[wave][1][tok];
      const float ga2 = pre0.z + s_eix[wave][2][tok];
      const float ga3 = pre0.w + s_eix[wave][3][tok];
      const float ig = sigm(ga0), fg = sigm(ga1);
      const float gg = tanhf(ga2), og = sigm(ga3);
      c1 = fg * c1 + ig * gg;
      const float hn = og * tanhf(c1);
      if (lane == 0) {
        const int j = wg * 4 + wave;
        if (t == LEN - 1) {
          __hip_atomic_store(&c1buf[j], c1, __ATOMIC_RELAXED, AGENT);
          asm volatile("s_waitcnt vmcnt(0)" ::: "memory");
        }
        const u64 x = ((u64)tag << 32) | (u64)__float_as_uint(hn);
        __hip_atomic_store(&h1s[pw * H + j], x, __ATOMIC_RELAXED, AGENT);
      }
      // off-critical prep for B: wh1 . h2(t-1)
      pre1 = dot4rows(wlds, 32 + wave * 4, h2p, g16, r16);
    }
    // all 512 threads: poll own slot pair, stage f16 pair into LDS
    {
      u64* s0 = &h1s[pw * H + 2 * tid];
      u64 a, b;
      for (;;) {
        a = __hip_atomic_load(s0, __ATOMIC_RELAXED, AGENT);
        b = __hip_atomic_load(s0 + 1, __ATOMIC_RELAXED, AGENT);
        if ((unsigned)(a >> 32) == tag && (unsigned)(b >> 32) == tag) break;
        __builtin_amdgcn_s_sleep(1);
      }
      __half2 hh = __floats2half2_rn(__uint_as_float((unsigned)a),
                                     __uint_as_float((unsigned)b));
      h1p[tid] = *(unsigned*)&hh;
    }
    __syncthreads();

    // ---------- Phase B: layer-1 gates = wi1.h1(t) + pre1; publish h2 ----------
    if (wave < 4) {
      const float4 d = dot4rows(wlds, 16 + wave * 4, h1p, g16, r16);
      const float gb0 = d.x + pre1.x + bs1[0];
      const float gb1 = d.y + pre1.y + bs1[1];
      const float gb2 = d.z + pre1.z + bs1[2];
      const float gb3 = d.w + pre1.w + bs1[3];
      const float ig = sigm(gb0), fg = sigm(gb1);
      const float gg = tanhf(gb2), og = sigm(gb3);
      c2 = fg * c2 + ig * gg;
      const float hn = og * tanhf(c2);
      if (lane == 0) {
        const int j = wg * 4 + wave;
        if (t == LEN - 1) {
          __hip_atomic_store(&c2buf[j], c2, __ATOMIC_RELAXED, AGENT);
          asm volatile("s_waitcnt vmcnt(0)" ::: "memory");
        }
        const u64 x = ((u64)tag << 32) | (u64)__float_as_uint(hn);
        __hip_atomic_store(&h2s[pw * H + j], x, __ATOMIC_RELAXED, AGENT);
      }
      // off-critical prep for next A: wh0 . h1(t)
      pre0 = dot4rows(wlds, 0 + wave * 4, h1p, g16, r16);
    }
    {
      u64* s0 = &h2s[pw * H + 2 * tid];
      u64 a, b;
      for (;;) {
        a = __hip_atomic_load(s0, __ATOMIC_RELAXED, AGENT);
        b = __hip_atomic_load(s0 + 1, __ATOMIC_RELAXED, AGENT);
        if ((unsigned)(a >> 32) == tag && (unsigned)(b >> 32) == tag) break;
        __builtin_amdgcn_s_sleep(1);
      }
      __half2 hh = __floats2half2_rn(__uint_as_float((unsigned)a),
                                     __uint_as_float((unsigned)b));
      h2p[tid] = *(unsigned*)&hh;
    }
    __syncthreads();

    // ---------- Phase C: fc logits + per-thread argmax ----------
    if (wave >= 4) {                      // rows 0..15 on waves 4..7
      const float4 d = dot4rows(wlds, 48 + (wave - 4) * 4, h2p, g16, r16);
      const float val = (lane == 0) ? d.x : (lane == 1) ? d.y
                       : (lane == 2) ? d.z : d.w;
      if (lane < 4) {
        const int v = (wave - 4) * 4 + lane;
        s_logits[v] = val + s_bfc[v];
      }
    } else if (wave < 2) {                // rows 16,17 on waves 0,1 (64-lane dot)
      const unsigned* wr = wlds[64 + wave];
      float a = 0.f;
#pragma unroll
      for (int k = 0; k < 4; ++k) {       // 4 x 128 u32 = 512 u32 = 1024 f16
        uint2 w = *(const uint2*)(wr + 2 * lane + 128 * k);
        uint2 h = *(const uint2*)(h2p + 2 * lane + 128 * k);
        a = fdot2_(w.x, h.x, a);
        a = fdot2_(w.y, h.y, a);
      }
      a = wred64(a);
      if (lane == 0) s_logits[16 + wave] = a + s_bfc[16 + wave];
    }
    __syncthreads();
    {
      const int node_end = ((t >> 1) % 10) / 2 + 3;
      float bv = -INFINITY;
      int bi = 0;
      for (int v = 0; v < V; ++v) {
        const bool m = (t & 1) ? (v >= NUM_NODES) : (v >= 1 && v < node_end);
        const float lv = s_logits[v];
        if (m && lv > bv) { bv = lv; bi = v; }
      }
      tok = bi;
    }
    if (wg == 0) {
      out_tok[t * BATCH + tid] = (float)tok;
      if (t == LEN - 1) {
        float mx = -INFINITY;
        for (int v = 0; v < V; ++v) mx = fmaxf(mx, s_logits[v]);
        float s = 0.f;
        for (int v = 0; v < V; ++v) s += expf(s_logits[v] - mx);
        const float lse = mx + logf(s);
        for (int i = tid; i < BATCH * V; i += NT)
          out_outs[i] = s_logits[i % V] - lse;
      }
    }
  }

  // ---------- Final outputs ----------
  {
    const float cv1a = __hip_atomic_load(&c1buf[2 * tid],     __ATOMIC_RELAXED, AGENT);
    const float cv1b = __hip_atomic_load(&c1buf[2 * tid + 1], __ATOMIC_RELAXED, AGENT);
    const float cv2a = __hip_atomic_load(&c2buf[2 * tid],     __ATOMIC_RELAXED, AGENT);
    const float cv2b = __hip_atomic_load(&c2buf[2 * tid + 1], __ATOMIC_RELAXED, AGENT);
    const half2v v1 = __builtin_bit_cast(half2v, h1p[tid]);
    const half2v v2 = __builtin_bit_cast(half2v, h2p[tid]);
#pragma unroll
    for (int rr = 0; rr < 4; ++rr) {
      const int r = wg + rr * NWG;      // row in [0, 1024)
      const int l = r >> 9;             // layer
      float* hd = out_hf + (size_t)r * H + 2 * tid;
      float* cd = out_cf + (size_t)r * H + 2 * tid;
      hd[0] = l ? (float)v2.x : (float)v1.x;
      hd[1] = l ? (float)v2.y : (float)v1.y;
      cd[0] = l ? cv2a : cv1a;
      cd[1] = l ? cv2b : cv1b;
    }
  }
}

extern "C" void kernel_launch(void* const* d_in, const int* in_sizes, int n_in,
                              void* d_out, int out_size, void* d_ws, size_t ws_size,
                              hipStream_t stream) {
  const int*   x0   = (const int*)d_in[0];
  const float* emb  = (const float*)d_in[1];
  const float* w_ih = (const float*)d_in[2];
  const float* w_hh = (const float*)d_in[3];
  const float* b_ih = (const float*)d_in[4];
  const float* b_hh = (const float*)d_in[5];
  const float* w_fc = (const float*)d_in[6];
  const float* b_fc = (const float*)d_in[7];
  float* ws = (float*)d_ws;

  hipLaunchKernelGGL(init_ws_kernel, dim3((WS_ZERO_U32 + 255) / 256), dim3(256), 0, stream,
                     (unsigned*)ws, WS_ZERO_U32);
  hipLaunchKernelGGL(decoder_kernel, dim3(NWG), dim3(NT), 0, stream,
                     x0, emb, w_ih, w_hh, b_ih, b_hh, w_fc, b_fc,
                     (float*)d_out, ws);
}